// Round 1
// baseline (113.896 us; speedup 1.0000x reference)
//
#include <hip/hip_runtime.h>
#include <hip/hip_bf16.h>

// u_mul_v: out[e, :] = h[src[e], :] * h[dst[e], :]
// h: [10000, 128] f32, src/dst: [640000] int, out: [640000, 128] f32.
// Memory-bound: 327.7 MB store dominates; h (5.1 MB) lives in L2/L3.
// Layout: 32 consecutive lanes own one edge; each lane does one float4
// (16 B) of the 128-float row -> 512 B contiguous per 32 lanes for both
// gathers and the store.

__global__ __launch_bounds__(256) void u_mul_v_kernel(
    const float4* __restrict__ h4,
    const int* __restrict__ src,
    const int* __restrict__ dst,
    float4* __restrict__ out4,
    int n_f4)   // total float4 elements = E * 32
{
    int stride = gridDim.x * blockDim.x;
    for (int i = blockIdx.x * blockDim.x + threadIdx.x; i < n_f4; i += stride) {
        int e = i >> 5;        // edge index
        int c = i & 31;        // float4 chunk within the 128-float row
        int s = src[e];        // same addr across 32 lanes -> broadcast
        int d = dst[e];
        float4 a = h4[(size_t)s * 32 + c];
        float4 b = h4[(size_t)d * 32 + c];
        float4 r;
        r.x = a.x * b.x;
        r.y = a.y * b.y;
        r.z = a.z * b.z;
        r.w = a.w * b.w;
        out4[i] = r;
    }
}

extern "C" void kernel_launch(void* const* d_in, const int* in_sizes, int n_in,
                              void* d_out, int out_size, void* d_ws, size_t ws_size,
                              hipStream_t stream) {
    const float4* h4 = (const float4*)d_in[0];
    const int* src   = (const int*)d_in[1];
    const int* dst   = (const int*)d_in[2];
    float4* out4     = (float4*)d_out;

    int n_edges = in_sizes[1];          // 640000
    int n_f4 = n_edges * 32;            // 20,480,000 float4 elements

    int block = 256;
    int grid = 2048;                    // grid-stride; ~8 blocks/CU
    u_mul_v_kernel<<<grid, block, 0, stream>>>(h4, src, dst, out4, n_f4);
}

// Round 2
// 83.004 us; speedup vs baseline: 1.3722x; 1.3722x over previous
//
#include <hip/hip_runtime.h>
#include <hip/hip_bf16.h>

// u_mul_v: out[e, :] = h[src[e], :] * h[dst[e], :]
// h: [10000, 128] f32, src/dst: [640000] int32, out: [640000, 128] f32.
// Memory-bound streaming write (327.7 MB); h (5.1 MB) should stay cache
// resident. Strategy:
//   - 32 lanes per edge, one float4 (16 B) per lane -> every load/store
//     instruction is a fully coalesced 1 KB wave access.
//   - U=4 explicit unroll, phases clustered (idx loads | gathers | stores)
//     so 4 independent latency chains are in flight per thread.
//   - Nontemporal stores: keep the 327 MB write stream from evicting h
//     out of the per-XCD L2s.

using f32x4 = __attribute__((ext_vector_type(4))) float;

constexpr int U = 4;

__global__ __launch_bounds__(256) void u_mul_v_kernel(
    const f32x4* __restrict__ h4,
    const int* __restrict__ src,
    const int* __restrict__ dst,
    f32x4* __restrict__ out4,
    int n_f4)   // total float4 elements = E * 32
{
    const int T = gridDim.x * blockDim.x;
    const int tid = blockIdx.x * blockDim.x + threadIdx.x;

    int s[U], d[U], c[U];
    bool ok[U];

    // Phase 1: all index loads (same addr across 32 lanes -> L1 broadcast)
#pragma unroll
    for (int u = 0; u < U; u++) {
        int i = tid + u * T;
        ok[u] = (i < n_f4);
        int e = i >> 5;
        c[u] = i & 31;
        s[u] = ok[u] ? src[e] : 0;
        d[u] = ok[u] ? dst[e] : 0;
    }

    // Phase 2: all gathers (cache-resident h)
    f32x4 a[U], b[U];
#pragma unroll
    for (int u = 0; u < U; u++) {
        a[u] = h4[(size_t)s[u] * 32 + c[u]];
        b[u] = h4[(size_t)d[u] * 32 + c[u]];
    }

    // Phase 3: multiply + nontemporal streaming stores
#pragma unroll
    for (int u = 0; u < U; u++) {
        if (ok[u]) {
            f32x4 r = a[u] * b[u];
            __builtin_nontemporal_store(r, &out4[tid + u * T]);
        }
    }
}

extern "C" void kernel_launch(void* const* d_in, const int* in_sizes, int n_in,
                              void* d_out, int out_size, void* d_ws, size_t ws_size,
                              hipStream_t stream) {
    const f32x4* h4 = (const f32x4*)d_in[0];
    const int* src  = (const int*)d_in[1];
    const int* dst  = (const int*)d_in[2];
    f32x4* out4     = (f32x4*)d_out;

    int n_edges = in_sizes[1];          // 640000
    int n_f4 = n_edges * 32;            // 20,480,000 float4 elements

    int block = 256;
    int grid = (n_f4 + block * U - 1) / (block * U);   // 20000 blocks
    u_mul_v_kernel<<<grid, block, 0, stream>>>(h4, src, dst, out4, n_f4);
}